// Round 9
// baseline (238.152 us; speedup 1.0000x reference)
//
#include <hip/hip_runtime.h>
#include <hip/hip_fp16.h>

#define N_NODES 65536
#define N_EDGES 1048576
#define F_IN    16
#define H       64
#define N_GRAPHS 32
#define NPG     2048
#define OUT_F   12
#define KPG     (NPG * H)
#define BUCKET_CAP 5120   // per-bucket padded region; counts ~4096 +/- 64 (16 sigma margin)

// ================================================================ CSR build (single persistent kernel)
// Edges pack into uint32: src (16b) | dst (16b) << 16. Bucket = dst>>8.
// Phase A (binA): LDS-staged bin into padded per-bucket regions (atomic reservation).
// -- software grid barrier (256 blocks = 1/CU, co-residency guaranteed) --
// Phase B (binB): per-bucket LDS counting sort -> nbr (ushort), rowse (start,end),
//                 fused g1h = fp16(dinv*x) and bias-init of out.

struct BinAS { int hist[256]; int sc[256]; int bnd[257]; int lcur[256]; int blkBase[256];
               unsigned int staged[4096]; };
struct BinBS { int hist[256]; int sc[256]; int off[256]; int cur[256];
               unsigned short outS[8192]; };

__global__ __launch_bounds__(256) void csr_fused_kernel(const int* __restrict__ src,
        const int* __restrict__ dst, int* __restrict__ gCursor, int* __restrict__ bar,
        unsigned int* __restrict__ binned, const float* __restrict__ x,
        const float* __restrict__ bfc, int2* __restrict__ rowse,
        unsigned short* __restrict__ nbr, __half2* __restrict__ g1h,
        float* __restrict__ out) {
    __shared__ __align__(16) char sm[21760];
    int b = blockIdx.x, t = threadIdx.x;

    { // ---- Phase A: binA
        BinAS& A = *reinterpret_cast<BinAS*>(sm);
        A.hist[t] = 0; A.lcur[t] = 0;
        __syncthreads();
        int e0 = b * 4096;
        unsigned int rec[16];
#pragma unroll
        for (int i = 0; i < 16; i++) {
            int e = e0 + i * 256 + t;
            unsigned int s = (unsigned int)src[e];
            unsigned int d = (unsigned int)dst[e];
            rec[i] = s | (d << 16);
            atomicAdd(&A.hist[d >> 8], 1);
        }
        __syncthreads();
        int cnt = A.hist[t];
        if (cnt) A.blkBase[t] = atomicAdd(&gCursor[t], cnt);  // reserve in bucket t's region
        A.sc[t] = cnt;
        __syncthreads();
        for (int off = 1; off < 256; off <<= 1) {
            int v = (t >= off) ? A.sc[t - off] : 0;
            __syncthreads();
            A.sc[t] += v;
            __syncthreads();
        }
        A.bnd[t] = A.sc[t] - cnt;
        if (t == 255) A.bnd[256] = 4096;
        __syncthreads();
#pragma unroll
        for (int i = 0; i < 16; i++) {
            int bb = rec[i] >> 24;
            int pos = A.bnd[bb] + atomicAdd(&A.lcur[bb], 1);
            A.staged[pos] = rec[i];
        }
        __syncthreads();
        for (int i = t; i < 4096; i += 256) {
            int lo = 0;
#pragma unroll
            for (int s2 = 128; s2 > 0; s2 >>= 1)
                if (A.bnd[lo + s2] <= i) lo += s2;
            binned[(size_t)lo * BUCKET_CAP + A.blkBase[lo] + (i - A.bnd[lo])] = A.staged[i];
        }
    }

    // ---- software grid barrier (release -> count -> acquire)
    __syncthreads();
    if (t == 0) {
        __threadfence();  // release: flush binned/gCursor visibility to agent scope
        __hip_atomic_fetch_add(bar, 1, __ATOMIC_ACQ_REL, __HIP_MEMORY_SCOPE_AGENT);
        while (__hip_atomic_load(bar, __ATOMIC_ACQUIRE, __HIP_MEMORY_SCOPE_AGENT) < 256)
            __builtin_amdgcn_s_sleep(2);
    }
    __syncthreads();
    __threadfence();      // acquire side for all threads

    { // ---- Phase B: binB + g1h + out bias
        BinBS& B = *reinterpret_cast<BinBS*>(sm);
        int base = b * BUCKET_CAP;
        int cnt  = gCursor[b];
        B.hist[t] = 0; B.cur[t] = 0;
        __syncthreads();
        for (int i = t; i < cnt; i += 256) {
            unsigned int r = binned[base + i];
            atomicAdd(&B.hist[(r >> 16) & 255], 1);
        }
        __syncthreads();
        int c = B.hist[t];
        B.sc[t] = c;
        __syncthreads();
        for (int o = 1; o < 256; o <<= 1) {
            int v = (t >= o) ? B.sc[t - o] : 0;
            __syncthreads();
            B.sc[t] += v;
            __syncthreads();
        }
        B.off[t] = B.sc[t] - c;
        int nd = (b << 8) + t;
        int start = base + B.sc[t] - c;
        rowse[nd] = make_int2(start, start + c);
        float dv = rsqrtf((float)(c + 1));   // deg = indeg + self-loop
        {   // fused g1h = fp16(dv * x[nd])
            const float4* xr = (const float4*)(x + (size_t)nd * F_IN);
            float4 x0 = xr[0], x1 = xr[1], x2 = xr[2], x3 = xr[3];
            __half2* gr = g1h + nd * 8;
            gr[0] = __floats2half2_rn(x0.x * dv, x0.y * dv);
            gr[1] = __floats2half2_rn(x0.z * dv, x0.w * dv);
            gr[2] = __floats2half2_rn(x1.x * dv, x1.y * dv);
            gr[3] = __floats2half2_rn(x1.z * dv, x1.w * dv);
            gr[4] = __floats2half2_rn(x2.x * dv, x2.y * dv);
            gr[5] = __floats2half2_rn(x2.z * dv, x2.w * dv);
            gr[6] = __floats2half2_rn(x3.x * dv, x3.y * dv);
            gr[7] = __floats2half2_rn(x3.z * dv, x3.w * dv);
        }
        __syncthreads();
        for (int i = t; i < cnt; i += 256) {
            unsigned int r = binned[base + i];
            int nloc = (r >> 16) & 255;
            int pos = B.off[nloc] + atomicAdd(&B.cur[nloc], 1);
            B.outS[pos] = (unsigned short)(r & 0xFFFF);
        }
        __syncthreads();
        for (int i = t; i < cnt; i += 256) nbr[base + i] = B.outS[i];
        if (b == 0)
            for (int i = t; i < N_GRAPHS * OUT_F; i += 256) out[i] = bfc[i % OUT_F];
    }
}

// ================================================================ layer 1 fused (full TLP: wave per node)
__global__ __launch_bounds__(256) void agg1gemm1_kernel(const __half2* __restrict__ g1h,
                                                        const int2* __restrict__ rowse,
                                                        const unsigned short* __restrict__ nbr,
                                                        const float* __restrict__ W1,
                                                        const float* __restrict__ b1,
                                                        __half* __restrict__ g2h) {
    __shared__ float Ws[F_IN * H];
    __shared__ float bs[H];
    int t = threadIdx.x;
    for (int i = t; i < F_IN * H; i += 256) Ws[i] = W1[i];
    if (t < H) bs[t] = b1[t];
    __syncthreads();
    int v    = (blockIdx.x << 2) + (t >> 6);
    int lane = t & 63;
    int f2   = lane & 7;
    int sub  = lane >> 3;
    int2 rr = rowse[v];
    int r0 = rr.x, r1 = rr.y;
    float ax = 0.f, ay = 0.f;
    for (int base = r0; base < r1; base += 64) {
        int er = min(64, r1 - base);
        int nb = (int)nbr[base + lane];
        int j = 0;
        for (; j + 16 <= er; j += 16) {
            int u0 = __shfl(nb, j + sub, 64);
            int u1 = __shfl(nb, j + 8 + sub, 64);
            float2 x0 = __half22float2(g1h[(u0 << 3) + f2]);
            float2 x1 = __half22float2(g1h[(u1 << 3) + f2]);
            ax += x0.x + x1.x;
            ay += x0.y + x1.y;
        }
        for (; j < er; j += 8) {
            int idx = j + sub;
            int u = __shfl(nb, idx < er ? idx : 0, 64);
            float2 xv = __half22float2(g1h[(u << 3) + f2]);
            if (idx < er) { ax += xv.x; ay += xv.y; }
        }
    }
    ax += __shfl_xor(ax, 8, 64);  ax += __shfl_xor(ax, 16, 64);  ax += __shfl_xor(ax, 32, 64);
    ay += __shfl_xor(ay, 8, 64);  ay += __shfl_xor(ay, 16, 64);  ay += __shfl_xor(ay, 32, 64);
    float dv = rsqrtf((float)(r1 - r0 + 1));
    float2 sv = __half22float2(g1h[(v << 3) + f2]);
    float a1x = dv * (ax + sv.x);
    float a1y = dv * (ay + sv.y);
    // gemm1 appendix: lane p (<8) holds feature pair p
    float s = bs[lane];
#pragma unroll
    for (int p = 0; p < 8; p++) {
        s += __shfl(a1x, p, 64) * Ws[(2 * p) * H + lane]
           + __shfl(a1y, p, 64) * Ws[(2 * p + 1) * H + lane];
    }
    g2h[(v << 6) + lane] = __float2half(dv * tanhf(s));
}

// ================================================================ layer 2 agg (wave per node)
__global__ __launch_bounds__(256) void agg2_kernel(const __half2* __restrict__ g2h,
                                                   const int2* __restrict__ rowse,
                                                   const unsigned short* __restrict__ nbr,
                                                   float2* __restrict__ a2) {
    int v    = (blockIdx.x * blockDim.x + threadIdx.x) >> 6;
    int lane = threadIdx.x & 63;
    int f2   = lane & 31;
    int sub  = lane >> 5;
    int2 rr = rowse[v];
    int r0 = rr.x, r1 = rr.y;
    float ax = 0.f, ay = 0.f;
    for (int base = r0; base < r1; base += 64) {
        int er = min(64, r1 - base);
        int nb = (int)nbr[base + lane];
        int j = 0;
        for (; j + 8 <= er; j += 8) {
            int u0 = __shfl(nb, j + sub, 64);
            int u1 = __shfl(nb, j + 2 + sub, 64);
            int u2 = __shfl(nb, j + 4 + sub, 64);
            int u3 = __shfl(nb, j + 6 + sub, 64);
            float2 x0 = __half22float2(g2h[(u0 << 5) + f2]);
            float2 x1 = __half22float2(g2h[(u1 << 5) + f2]);
            float2 x2 = __half22float2(g2h[(u2 << 5) + f2]);
            float2 x3 = __half22float2(g2h[(u3 << 5) + f2]);
            ax += (x0.x + x1.x) + (x2.x + x3.x);
            ay += (x0.y + x1.y) + (x2.y + x3.y);
        }
        for (; j < er; j += 2) {
            int idx = j + sub;
            int u = __shfl(nb, idx < er ? idx : 0, 64);
            float2 xv = __half22float2(g2h[(u << 5) + f2]);
            if (idx < er) { ax += xv.x; ay += xv.y; }
        }
    }
    ax += __shfl_xor(ax, 32, 64);
    ay += __shfl_xor(ay, 32, 64);
    if (sub == 0) {
        float dv = rsqrtf((float)(r1 - r0 + 1));
        float2 sv = __half22float2(g2h[(v << 5) + f2]);
        a2[(v << 5) + f2] = make_float2(dv * (ax + sv.x), dv * (ay + sv.y));
    }
}

// ================================================================ gemm2 + FC fused
// block (kc 0..127, gg 0..3) owns exactly the 128 nodes (8 graphs x 16 positions)
// whose h2 feeds k-range [kc*1024, kc*1024+1024) of graphs [gg*8, gg*8+8).
__global__ __launch_bounds__(256) void fc2_kernel(const float* __restrict__ a2,
                                                  const float* __restrict__ W2,
                                                  const float* __restrict__ b2,
                                                  const float* __restrict__ Wfc,
                                                  float* __restrict__ out) {
    __shared__ float Ws[H * H];        // 16 KB
    __shared__ float bs2[H];
    __shared__ float hs[128 * 65];     // 33.3 KB, stride-65 (bank-clean)
    __shared__ float red[4][96];
    int t  = threadIdx.x;
    int kc = blockIdx.x & 127;
    int gg = blockIdx.x >> 7;
    for (int i = t; i < H * H; i += 256) Ws[i] = W2[i];
    if (t < H) bs2[t] = b2[t];
    // stage a2 rows of our 128 nodes (local n = g*16 + p)
    for (int i = t; i < 2048; i += 256) {
        int n = i >> 4, q = i & 15;
        int node = ((gg << 3) + (n >> 4)) * NPG + (kc << 4) + (n & 15);
        float4 vv = ((const float4*)a2)[node * 16 + q];
        float* dp = hs + n * 65 + q * 4;
        dp[0] = vv.x; dp[1] = vv.y; dp[2] = vv.z; dp[3] = vv.w;
    }
    __syncthreads();
    // h2 = tanh(a2 @ W2 + b2): 2 threads per node, 32 feats each
    int n  = t >> 1;
    int fb = (t & 1) << 5;
    float s[32];
    {
        const float* arow = hs + n * 65;
#pragma unroll
        for (int f = 0; f < 32; f++) s[f] = bs2[fb + f];
        for (int k = 0; k < H; k++) {
            float a = arow[k];
#pragma unroll
            for (int f = 0; f < 32; f++) s[f] += a * Ws[k * H + fb + f];
        }
#pragma unroll
        for (int f = 0; f < 32; f++) s[f] = tanhf(s[f]);
    }
    __syncthreads();   // all a2 reads complete
#pragma unroll
    for (int f = 0; f < 32; f++) hs[n * 65 + fb + f] = s[f];
    __syncthreads();
    // fc accumulation
    float acc[8][OUT_F];
#pragma unroll
    for (int g = 0; g < 8; g++)
#pragma unroll
        for (int j = 0; j < OUT_F; j++) acc[g][j] = 0.f;
#pragma unroll
    for (int i = 0; i < 4; i++) {
        int klocal = (i << 8) + t;             // 0..1023
        int p = klocal >> 6, feat = klocal & 63;
        size_t kglob = ((size_t)kc << 10) + klocal;
        const float4* w4 = (const float4*)(Wfc + kglob * OUT_F);
        float4 w0 = w4[0], w1 = w4[1], w2 = w4[2];
#pragma unroll
        for (int g = 0; g < 8; g++) {
            float hv = hs[(g * 16 + p) * 65 + feat];
            acc[g][0] += hv * w0.x;  acc[g][1] += hv * w0.y;
            acc[g][2] += hv * w0.z;  acc[g][3] += hv * w0.w;
            acc[g][4] += hv * w1.x;  acc[g][5] += hv * w1.y;
            acc[g][6] += hv * w1.z;  acc[g][7] += hv * w1.w;
            acc[g][8] += hv * w2.x;  acc[g][9] += hv * w2.y;
            acc[g][10] += hv * w2.z; acc[g][11] += hv * w2.w;
        }
    }
#pragma unroll
    for (int g = 0; g < 8; g++)
#pragma unroll
        for (int j = 0; j < OUT_F; j++) {
            float v = acc[g][j];
            v += __shfl_xor(v, 1, 64);  v += __shfl_xor(v, 2, 64);
            v += __shfl_xor(v, 4, 64);  v += __shfl_xor(v, 8, 64);
            v += __shfl_xor(v, 16, 64); v += __shfl_xor(v, 32, 64);
            acc[g][j] = v;
        }
    int w = t >> 6;
    if ((t & 63) == 0) {
#pragma unroll
        for (int g = 0; g < 8; g++)
#pragma unroll
            for (int j = 0; j < OUT_F; j++) red[w][g * OUT_F + j] = acc[g][j];
    }
    __syncthreads();
    if (t < 96)
        atomicAdd(&out[gg * 96 + t], red[0][t] + red[1][t] + red[2][t] + red[3][t]);
}

// ================================================================ launcher
extern "C" void kernel_launch(void* const* d_in, const int* in_sizes, int n_in,
                              void* d_out, int out_size, void* d_ws, size_t ws_size,
                              hipStream_t stream) {
    const float* x    = (const float*)d_in[0];
    const int*   edge = (const int*)d_in[1];
    const int*   src  = edge;
    const int*   dst  = edge + N_EDGES;
    const float* W1  = (const float*)d_in[3];
    const float* b1  = (const float*)d_in[4];
    const float* W2  = (const float*)d_in[5];
    const float* b2  = (const float*)d_in[6];
    const float* Wfc = (const float*)d_in[7];
    const float* bfc = (const float*)d_in[8];
    float* out = (float*)d_out;

    char* p = (char*)d_ws;
    auto alloc = [&](size_t n) { char* r = p; p += (n + 255) & ~(size_t)255; return r; };
    int*   gCursor = (int*)alloc(256 * 4 + 64);     // + barrier counter, zeroed together
    int*   bar     = gCursor + 256;
    unsigned int* binned = (unsigned int*)alloc((size_t)256 * BUCKET_CAP * 4);
    int2*  rowse   = (int2*)alloc((size_t)N_NODES * 8);
    unsigned short* nbr = (unsigned short*)alloc((size_t)256 * BUCKET_CAP * 2 + 256);
    __half* g1h    = (__half*)alloc((size_t)N_NODES * F_IN * 2);
    __half* g2h    = (__half*)alloc((size_t)N_NODES * H * 2);
    float* a2      = (float*)alloc((size_t)N_NODES * H * 4);

    hipMemsetAsync(gCursor, 0, 256 * 4 + 64, stream);
    csr_fused_kernel<<<256, 256, 0, stream>>>(src, dst, gCursor, bar, binned, x, bfc,
                                              rowse, nbr, (__half2*)g1h, out);
    agg1gemm1_kernel<<<N_NODES / 4, 256, 0, stream>>>((const __half2*)g1h, rowse, nbr,
                                                      W1, b1, g2h);
    agg2_kernel<<<N_NODES / 4, 256, 0, stream>>>((const __half2*)g2h, rowse, nbr,
                                                 (float2*)a2);
    fc2_kernel<<<512, 256, 0, stream>>>(a2, W2, b2, Wfc, out);
}